// Round 2
// baseline (316.217 us; speedup 1.0000x reference)
//
#include <hip/hip_runtime.h>
#include <cstddef>

#define EPS_ 1e-5f
#define SCALE_ 0.1767766952966369f   // 1/sqrt(32)

__device__ __forceinline__ float gelu_f(float x) {
    return 0.5f * x * (1.0f + erff(x * 0.7071067811865476f));
}

// -------- LayerNorm over C=256, one wave per row --------
__global__ __launch_bounds__(256) void ln_kernel(const float* __restrict__ x,
                                                 const float* __restrict__ g,
                                                 const float* __restrict__ b,
                                                 float* __restrict__ out) {
    int wid = threadIdx.x >> 6, lane = threadIdx.x & 63;
    int row = blockIdx.x * 4 + wid;
    const float4 xv = *(const float4*)(x + (size_t)row * 256 + lane * 4);
    float s  = xv.x + xv.y + xv.z + xv.w;
    float sq = xv.x*xv.x + xv.y*xv.y + xv.z*xv.z + xv.w*xv.w;
#pragma unroll
    for (int m = 1; m < 64; m <<= 1) { s += __shfl_xor(s, m); sq += __shfl_xor(sq, m); }
    float mean = s * (1.0f/256.0f);
    float var  = sq * (1.0f/256.0f) - mean*mean;
    float rstd = rsqrtf(var + EPS_);
    float4 gv = *(const float4*)(g + lane*4);
    float4 bv = *(const float4*)(b + lane*4);
    float4 o;
    o.x = (xv.x-mean)*rstd*gv.x + bv.x;
    o.y = (xv.y-mean)*rstd*gv.y + bv.y;
    o.z = (xv.z-mean)*rstd*gv.z + bv.z;
    o.w = (xv.w-mean)*rstd*gv.w + bv.w;
    *(float4*)(out + (size_t)row * 256 + lane * 4) = o;
}

// -------- Generic tiled f32 GEMM: C = A[M,K] @ B[K,N] (+bias)(gelu)(+resid) --------
template<bool BIAS, bool GACT, bool RESID, int KSPLIT>
__global__ __launch_bounds__(256) void gemm_kernel(
    const float* __restrict__ A, const float* __restrict__ Bm,
    const float* __restrict__ bias, const float* __restrict__ resid,
    float* __restrict__ Cout, int M, int N, int K) {
    __shared__ float As[16][68];
    __shared__ float Bs[16][64];
    int t = threadIdx.x;
    int bm = blockIdx.x, bn = blockIdx.y, kz = blockIdx.z;
    int kchunk = K / KSPLIT;
    int k0 = kz * kchunk;
    int tm = t >> 4, tn = t & 15;
    int la_m = t >> 2, la_k = (t & 3) << 2;
    int lb_k = t >> 4, lb_n = (t & 15) << 2;
    float acc[4][4] = {};
    const float* Aptr = A  + (size_t)(bm*64 + la_m) * K + k0 + la_k;
    const float* Bptr = Bm + (size_t)(k0 + lb_k) * N + bn*64 + lb_n;
    for (int kk = 0; kk < kchunk; kk += 16) {
        float4 a4 = *(const float4*)(Aptr + kk);
        float4 b4 = *(const float4*)(Bptr + (size_t)kk * N);
        __syncthreads();
        As[la_k+0][la_m] = a4.x;
        As[la_k+1][la_m] = a4.y;
        As[la_k+2][la_m] = a4.z;
        As[la_k+3][la_m] = a4.w;
        *(float4*)(&Bs[lb_k][lb_n]) = b4;
        __syncthreads();
#pragma unroll
        for (int k = 0; k < 16; ++k) {
            float4 av = *(const float4*)(&As[k][tm<<2]);
            float4 bv = *(const float4*)(&Bs[k][tn<<2]);
            acc[0][0] += av.x*bv.x; acc[0][1] += av.x*bv.y; acc[0][2] += av.x*bv.z; acc[0][3] += av.x*bv.w;
            acc[1][0] += av.y*bv.x; acc[1][1] += av.y*bv.y; acc[1][2] += av.y*bv.z; acc[1][3] += av.y*bv.w;
            acc[2][0] += av.z*bv.x; acc[2][1] += av.z*bv.y; acc[2][2] += av.z*bv.z; acc[2][3] += av.z*bv.w;
            acc[3][0] += av.w*bv.x; acc[3][1] += av.w*bv.y; acc[3][2] += av.w*bv.z; acc[3][3] += av.w*bv.w;
        }
    }
    int row0 = bm*64 + tm*4, col0 = bn*64 + tn*4;
    float4 bv4 = make_float4(0.f,0.f,0.f,0.f);
    if (BIAS) bv4 = *(const float4*)(bias + col0);
#pragma unroll
    for (int i2 = 0; i2 < 4; ++i2) {
        float4 r;
        r.x = acc[i2][0]; r.y = acc[i2][1]; r.z = acc[i2][2]; r.w = acc[i2][3];
        if (BIAS) { r.x += bv4.x; r.y += bv4.y; r.z += bv4.z; r.w += bv4.w; }
        if (GACT) { r.x = gelu_f(r.x); r.y = gelu_f(r.y); r.z = gelu_f(r.z); r.w = gelu_f(r.w); }
        if (RESID) {
            float4 rv = *(const float4*)(resid + (size_t)(row0+i2)*N + col0);
            r.x += rv.x; r.y += rv.y; r.z += rv.z; r.w += rv.w;
        }
        float* dst = Cout + (KSPLIT > 1 ? (size_t)kz * M * N : (size_t)0) + (size_t)(row0+i2)*N + col0;
        *(float4*)dst = r;
    }
}

// -------- Fused: logits[b*i][h][j] = (q_i . k_j + LN(GELU(rp[b,i,j,:]@w_rel + b_rel))[h]) * scale --------
// One wave handles (b,i) and 128 consecutive j. Lane owns c = 4*lane..4*lane+3.
__global__ __launch_bounds__(256) void rel_logits_kernel(
    const float* __restrict__ rp, const float* __restrict__ qkv,
    const float* __restrict__ w_rel, const float* __restrict__ b_rel,
    const float* __restrict__ g_reln, const float* __restrict__ b_reln,
    float* __restrict__ logits) {
    int bi = blockIdx.x;                 // b*512 + i
    int wid = threadIdx.x >> 6, lane = threadIdx.x & 63;
    int b = bi >> 9;
    int b0 = lane & 1, b1 = (lane >> 1) & 1, b2 = (lane >> 2) & 1;
    int hl = 4*b0 + 2*b1 + b2;           // head this lane ends up holding
    // preload w_rel rows c=4*lane..+3 (each row = 8 floats)
    float w[4][8];
    {
        const float* wr = w_rel + (size_t)lane * 32;
#pragma unroll
        for (int u = 0; u < 4; ++u) {
            float4 w0 = *(const float4*)(wr + u*8);
            float4 w1 = *(const float4*)(wr + u*8 + 4);
            w[u][0]=w0.x; w[u][1]=w0.y; w[u][2]=w0.z; w[u][3]=w0.w;
            w[u][4]=w1.x; w[u][5]=w1.y; w[u][6]=w1.z; w[u][7]=w1.w;
        }
    }
    float brel = b_rel[hl], grn = g_reln[hl], brn = b_reln[hl];
    float4 q4 = *(const float4*)(qkv + (size_t)bi * 768 + lane * 4);
    const float* rpb   = rp  + (size_t)bi * 512 * 256;
    const float* kbase = qkv + (size_t)b * 512 * 768 + 256;
    float* lrow = logits + ((size_t)bi * 8 + hl) * 512;
    int j0 = wid * 128;
    float jb0 = 0.f, jb1 = 0.f, jb2 = 0.f;
    for (int jj = 0; jj < 128; ++jj) {
        int j = j0 + jj;
        float4 r4 = *(const float4*)(rpb   + (size_t)j * 256 + lane * 4);
        float4 k4 = *(const float4*)(kbase + (size_t)j * 768 + lane * 4);
        // 8 head partials over this lane's 4 c's
        float p0 = r4.x*w[0][0] + r4.y*w[1][0] + r4.z*w[2][0] + r4.w*w[3][0];
        float p1 = r4.x*w[0][1] + r4.y*w[1][1] + r4.z*w[2][1] + r4.w*w[3][1];
        float p2 = r4.x*w[0][2] + r4.y*w[1][2] + r4.z*w[2][2] + r4.w*w[3][2];
        float p3 = r4.x*w[0][3] + r4.y*w[1][3] + r4.z*w[2][3] + r4.w*w[3][3];
        float p4 = r4.x*w[0][4] + r4.y*w[1][4] + r4.z*w[2][4] + r4.w*w[3][4];
        float p5 = r4.x*w[0][5] + r4.y*w[1][5] + r4.z*w[2][5] + r4.w*w[3][5];
        float p6 = r4.x*w[0][6] + r4.y*w[1][6] + r4.z*w[2][6] + r4.w*w[3][6];
        float p7 = r4.x*w[0][7] + r4.y*w[1][7] + r4.z*w[2][7] + r4.w*w[3][7];
        // q.k partial (this lane's c-range lies in head g = lane>>3); reduce within 8-lane group
        float pq = q4.x*k4.x + q4.y*k4.y + q4.z*k4.z + q4.w*k4.w;
        pq += __shfl_xor(pq, 1); pq += __shfl_xor(pq, 2); pq += __shfl_xor(pq, 4);
        // log-fold reduce of 8 rel partials across 64 lanes (lane ends with head hl)
        float f0 = (b0 ? p4 : p0) + __shfl_xor(b0 ? p0 : p4, 1);
        float f1 = (b0 ? p5 : p1) + __shfl_xor(b0 ? p1 : p5, 1);
        float f2 = (b0 ? p6 : p2) + __shfl_xor(b0 ? p2 : p6, 1);
        float f3 = (b0 ? p7 : p3) + __shfl_xor(b0 ? p3 : p7, 1);
        float e0 = (b1 ? f2 : f0) + __shfl_xor(b1 ? f0 : f2, 2);
        float e1 = (b1 ? f3 : f1) + __shfl_xor(b1 ? f1 : f3, 2);
        float S  = (b2 ? e1 : e0) + __shfl_xor(b2 ? e0 : e1, 4);
        S += __shfl_xor(S, 8); S += __shfl_xor(S, 16); S += __shfl_xor(S, 32);
        // GELU(exact) then LayerNorm over the 8 heads (held by the 8 lanes of each group)
        float val = S + brel;
        float gv = 0.5f * val * (1.0f + erff(val * 0.7071067811865476f));
        float sm = gv, sq = gv*gv;
        sm += __shfl_xor(sm, 1); sq += __shfl_xor(sq, 1);
        sm += __shfl_xor(sm, 2); sq += __shfl_xor(sq, 2);
        sm += __shfl_xor(sm, 4); sq += __shfl_xor(sq, 4);
        float mean = sm * 0.125f;
        float var  = sq * 0.125f - mean*mean;
        float reln = (gv - mean) * rsqrtf(var + EPS_) * grn + brn;
        // fetch qk for head hl (lives on lanes of group hl)
        float qk = __shfl(pq, (hl << 3) | (lane & 7));
        float lg = (qk + reln) * SCALE_;
        int ph = jj & 3;
        if      (ph == 0) jb0 = lg;
        else if (ph == 1) jb1 = lg;
        else if (ph == 2) jb2 = lg;
        else {
            if (lane < 8) {
                float4 o4 = make_float4(jb0, jb1, jb2, lg);
                *(float4*)(lrow + (j - 3)) = o4;
            }
        }
    }
}

// -------- row softmax over j=512, one wave per (b,i,h) row, in-place --------
__global__ __launch_bounds__(256) void softmax_kernel(float* __restrict__ lg) {
    int row = blockIdx.x * 4 + (threadIdx.x >> 6);
    int lane = threadIdx.x & 63;
    float* p = lg + (size_t)row * 512;
    float4 v0 = *(float4*)(p + lane*4);
    float4 v1 = *(float4*)(p + 256 + lane*4);
    float mx = fmaxf(fmaxf(fmaxf(v0.x,v0.y),fmaxf(v0.z,v0.w)),
                     fmaxf(fmaxf(v1.x,v1.y),fmaxf(v1.z,v1.w)));
#pragma unroll
    for (int m = 1; m < 64; m <<= 1) mx = fmaxf(mx, __shfl_xor(mx, m));
    v0.x = expf(v0.x-mx); v0.y = expf(v0.y-mx); v0.z = expf(v0.z-mx); v0.w = expf(v0.w-mx);
    v1.x = expf(v1.x-mx); v1.y = expf(v1.y-mx); v1.z = expf(v1.z-mx); v1.w = expf(v1.w-mx);
    float s = v0.x+v0.y+v0.z+v0.w + v1.x+v1.y+v1.z+v1.w;
#pragma unroll
    for (int m = 1; m < 64; m <<= 1) s += __shfl_xor(s, m);
    float inv = 1.0f / s;
    v0.x*=inv; v0.y*=inv; v0.z*=inv; v0.w*=inv;
    v1.x*=inv; v1.y*=inv; v1.z*=inv; v1.w*=inv;
    *(float4*)(p + lane*4) = v0;
    *(float4*)(p + 256 + lane*4) = v1;
}

// -------- o[b,i,h*32+d] = sum_j attn[(b*512+i)*8+h][j] * v[b,j,h,d]; wave = (b,h,i-pair) --------
__global__ __launch_bounds__(256) void attnv_kernel(const float* __restrict__ attn,
                                                    const float* __restrict__ qkv,
                                                    float* __restrict__ o) {
    int gw = blockIdx.x * 4 + (threadIdx.x >> 6);     // 0..4095
    int lane = threadIdx.x & 63;
    int ip = gw & 255, h = (gw >> 8) & 7, b = gw >> 11;
    int i = ip*2 + (lane >> 5);
    int d = lane & 31;
    const float* ar = attn + ((size_t)((b*512 + i)*8 + h)) * 512;
    const float* vb = qkv + (size_t)b*512*768 + 512 + h*32 + d;
    float acc = 0.f;
    for (int j = 0; j < 512; j += 4) {
        float4 a4 = *(const float4*)(ar + j);
        acc += a4.x * vb[(size_t)(j+0)*768];
        acc += a4.y * vb[(size_t)(j+1)*768];
        acc += a4.z * vb[(size_t)(j+2)*768];
        acc += a4.w * vb[(size_t)(j+3)*768];
    }
    o[(size_t)(b*512 + i)*256 + h*32 + d] = acc;
}

// -------- split-K combine for mlp2: out = resid + bias + sum_z part[z] --------
__global__ __launch_bounds__(256) void combine_kernel(const float* __restrict__ part,
                                                      const float* __restrict__ bias,
                                                      const float* __restrict__ resid,
                                                      float* __restrict__ out) {
    int f = blockIdx.x * 256 + threadIdx.x;   // 65536 float4s
    int e = f * 4;
    float4 r  = *(const float4*)(resid + e);
    float4 bv = *(const float4*)(bias + (e & 255));
    float4 p0 = *(const float4*)(part + e);
    float4 p1 = *(const float4*)(part + 262144 + e);
    float4 p2 = *(const float4*)(part + 524288 + e);
    float4 p3 = *(const float4*)(part + 786432 + e);
    float4 o4;
    o4.x = r.x + bv.x + p0.x + p1.x + p2.x + p3.x;
    o4.y = r.y + bv.y + p0.y + p1.y + p2.y + p3.y;
    o4.z = r.z + bv.z + p0.z + p1.z + p2.z + p3.z;
    o4.w = r.w + bv.w + p0.w + p1.w + p2.w + p3.w;
    *(float4*)(out + e) = o4;
}

extern "C" void kernel_launch(void* const* d_in, const int* in_sizes, int n_in,
                              void* d_out, int out_size, void* d_ws, size_t ws_size,
                              hipStream_t stream) {
    const float* x      = (const float*)d_in[0];
    const float* rp     = (const float*)d_in[1];
    const float* w_qkv  = (const float*)d_in[2];
    const float* w_proj = (const float*)d_in[3];
    const float* b_proj = (const float*)d_in[4];
    const float* w_rel  = (const float*)d_in[5];
    const float* b_rel  = (const float*)d_in[6];
    const float* g_reln = (const float*)d_in[7];
    const float* b_reln = (const float*)d_in[8];
    const float* g_n1   = (const float*)d_in[9];
    const float* b_n1   = (const float*)d_in[10];
    const float* g_n2   = (const float*)d_in[11];
    const float* b_n2   = (const float*)d_in[12];
    const float* w_mlp1 = (const float*)d_in[13];
    const float* b_mlp1 = (const float*)d_in[14];
    const float* w_mlp2 = (const float*)d_in[15];
    const float* b_mlp2 = (const float*)d_in[16];
    float* out = (float*)d_out;

    float* ws    = (float*)d_ws;
    float* ws_h   = ws;                   // 1024*256           (LN1 out; dead after qkv gemm)
    float* ws_qkv = ws_h   + 262144;      // 1024*768
    float* ws_lg  = ws_qkv + 786432;      // 1024*8*512         (dead after attnv)
    float* ws_o   = ws_lg  + 4194304;     // 1024*256
    float* ws_x1  = ws_o   + 262144;      // 1024*256
    float* ws_h2  = ws_h;                 // alias: LN2 out reuses LN1 region
    float* ws_hg  = ws_lg;                // alias: 1024*1024 in dead logits region
    float* ws_pt  = ws_lg  + 1048576;     // alias: 4*1024*256 in dead logits region

    // 1) h = LN1(x)
    ln_kernel<<<256, 256, 0, stream>>>(x, g_n1, b_n1, ws_h);
    // 2) qkv = h @ w_qkv   [1024,768]
    gemm_kernel<false,false,false,1><<<dim3(16,12,1), 256, 0, stream>>>(
        ws_h, w_qkv, nullptr, nullptr, ws_qkv, 1024, 768, 256);
    // 3) logits = (q.k + LN(GELU(rp@w_rel+b)))*scale  [1024][8][512]
    rel_logits_kernel<<<1024, 256, 0, stream>>>(rp, ws_qkv, w_rel, b_rel, g_reln, b_reln, ws_lg);
    // 4) softmax rows (in place)
    softmax_kernel<<<2048, 256, 0, stream>>>(ws_lg);
    // 5) o = attn @ v   [1024,256]
    attnv_kernel<<<1024, 256, 0, stream>>>(ws_lg, ws_qkv, ws_o);
    // 6) x1 = x + o @ w_proj + b_proj
    gemm_kernel<true,false,true,1><<<dim3(16,4,1), 256, 0, stream>>>(
        ws_o, w_proj, b_proj, x, ws_x1, 1024, 256, 256);
    // 7) h2 = LN2(x1)
    ln_kernel<<<256, 256, 0, stream>>>(ws_x1, g_n2, b_n2, ws_h2);
    // 8) hg = GELU(h2 @ w_mlp1 + b_mlp1)  [1024,1024]
    gemm_kernel<true,true,false,1><<<dim3(16,16,1), 256, 0, stream>>>(
        ws_h2, w_mlp1, b_mlp1, nullptr, ws_hg, 1024, 1024, 256);
    // 9) partials = hg @ w_mlp2 (split-K=4)
    gemm_kernel<false,false,false,4><<<dim3(16,4,4), 256, 0, stream>>>(
        ws_hg, w_mlp2, nullptr, nullptr, ws_pt, 1024, 256, 1024);
    // 10) out = x1 + b_mlp2 + sum partials
    combine_kernel<<<256, 256, 0, stream>>>(ws_pt, b_mlp2, ws_x1, out);
}